// Round 1
// baseline (153.815 us; speedup 1.0000x reference)
//
#include <hip/hip_runtime.h>
#include <math.h>

// N=4, R=16384, K=96. Output: rgb [65536*3] | depth [65536] | weights [65536*95]
#define NRAYS     65536
#define RGB_OFF   0
#define DEPTH_OFF (NRAYS * 3)
#define W_OFF     (NRAYS * 4)

#define RPB 16               // rays per tile (256 threads, 4 waves, 16 lanes/ray)
// input staging layout per buffer (floats); pads absorb lane-15 overreads
#define SHD_OFF 0            // 16*96 = 1536 used, pad to 1540
#define SHS_OFF 1540
#define SHR_OFF 3080         // 16*288 = 4608 used, pad to 4616
#define SH_TOTAL 7696        // 30784 B per buffer
// output staging (reuses the input regions after compute)
#define WST_OFF 0            // 16*95 = 1520 floats
#define CST_OFF 1540         // 48 floats rgb
#define DST_OFF 1600         // 16 floats depth

#define TPB 8                                  // tiles per persistent block
#define NBLOCKS (NRAYS / RPB / TPB)            // 512 blocks = 2/CU (61.6 KB LDS dbuf)

typedef float v4f __attribute__((ext_vector_type(4)));

#define DPPF(oldv, x, ctrl)                                                    \
    __int_as_float(__builtin_amdgcn_update_dpp(                                \
        __float_as_int(oldv), __float_as_int(x), (ctrl), 0xF, 0xF, false))

// raw-barrier discipline: counted waits + s_barrier, NEVER __syncthreads
// (__syncthreads drains vmcnt(0) and would kill the DMA pipeline).
#define WAITVM(N) asm volatile("s_waitcnt vmcnt(" #N ")" ::: "memory")
#define LGKM0     asm volatile("s_waitcnt lgkmcnt(0)" ::: "memory")
#define BARRIER()                                                              \
    do { __builtin_amdgcn_s_barrier(); asm volatile("" ::: "memory"); } while (0)

// 1-alpha = exp(-delta*softplus(x)) via HW transcendentals. absmax 7.8e-3 ok.
__device__ __forceinline__ float one_minus_alpha(float x, float delta) {
    const float L2E = 1.44269504088896340736f;
    float xl = x * L2E;
    float l2 = (x > 20.0f) ? xl
                           : __builtin_amdgcn_logf(1.0f + __builtin_amdgcn_exp2f(xl));
    return __builtin_amdgcn_exp2f(-delta * l2);
}

// async global->LDS DMA, 16 B/lane, aux=2 -> NT (streaming) cache policy.
__device__ __forceinline__ void gload_lds16(const float* g, float* l) {
    __builtin_amdgcn_global_load_lds(
        (const __attribute__((address_space(1))) void*)g,
        (__attribute__((address_space(3))) void*)l, 16, 0, 2);
}

// 30 wave-chunks of 1024 B over 4 waves. DMA count per wave: w0/w1=8, w2/w3=7.
__device__ __forceinline__ void stage_tile(const float* __restrict__ rgbs,
                                           const float* __restrict__ sigmas,
                                           const float* __restrict__ depths,
                                           int tile, float* buf, int w, int l64) {
    const float* gd = depths + (size_t)tile * (RPB * 96);
    const float* gs = sigmas + (size_t)tile * (RPB * 96);
    const float* gr = rgbs   + (size_t)tile * (RPB * 288);
    for (int c = w; c < 30; c += 4) {
        const float* src; float* dst;
        if (c < 6)       { src = gd + c * 256;        dst = buf + SHD_OFF + c * 256; }
        else if (c < 12) { src = gs + (c - 6) * 256;  dst = buf + SHS_OFF + (c - 6) * 256; }
        else             { src = gr + (c - 12) * 256; dst = buf + SHR_OFF + (c - 12) * 256; }
        gload_lds16(src + l64 * 4, dst + l64 * 4);
    }
}

// ---------------------------------------------------------------------------
// R9 = R8 compute, persistent + double-buffered pipeline (T3+T4):
//  - 512 persistent blocks x 8 contiguous tiles; XCD owns a contiguous 1/8.
//  - 2 x 30.8 KB LDS buffers; next tile's global->LDS DMA is issued BEFORE
//    compute of the current tile and stays in flight across all barriers.
//  - counted per-wave s_waitcnt vmcnt(N) (guaranteed-minimum store counts,
//    under-counting stores is the safe direction) + raw s_barrier.
// Tests whether R8's ~14.5us kernel was drain/latency-bound (expect ~10us)
// or L3-fabric-BW-bound (expect neutral -> roofline evidence).
// ---------------------------------------------------------------------------
__global__ __launch_bounds__(256) void integrate_kernel(
    const float* __restrict__ rgbs,     // [NRAYS, 96, 3]
    const float* __restrict__ sigmas,   // [NRAYS, 96]
    const float* __restrict__ depths,   // [NRAYS, 96]
    float* __restrict__ out)
{
    __shared__ float sh[2 * SH_TOTAL];

    const int t   = threadIdx.x;
    const int w   = t >> 6;
    const int l64 = t & 63;
    // XCD-contiguous: XCD x = blockIdx&7 owns tiles [x*512, (x+1)*512);
    // slot s = blockIdx>>3 takes 8 contiguous tiles within that range.
    const int tile0 = ((blockIdx.x & 7) << 9) | ((blockIdx.x >> 3) << 3);

    const int rb_ = t >> 4;             // ray within tile
    const int l   = t & 15;             // segment within ray
    const bool full = (l < 15);

    // prologue: stage tile 0 into buf 0
    stage_tile(rgbs, sigmas, depths, tile0, sh, w, l64);

    for (int i = 0; i < TPB; ++i) {
        float* buf = sh + (i & 1) * SH_TOTAL;
        const int tile = tile0 + i;

        // issue next tile's DMA into the other buffer (stays in flight
        // across the entire compute+store phase of this tile)
        if (i < TPB - 1)
            stage_tile(rgbs, sigmas, depths, tile + 1, sh + ((i + 1) & 1) * SH_TOTAL, w, l64);

        // wait until THIS tile's DMA has landed. Allowed-outstanding =
        // own next-tile DMA (8/8/7/7) + guaranteed-minimum own NT stores
        // from the previous iteration (4/2/1/1). In-order vmcnt retirement
        // means everything older (= this tile's DMA) is then complete.
        if (i == 0) {
            if (w < 2) { WAITVM(8); } else { WAITVM(7); }
        } else if (i < TPB - 1) {
            if      (w == 0) { WAITVM(12); }
            else if (w == 1) { WAITVM(10); }
            else             { WAITVM(8);  }
        } else {
            if      (w == 0) { WAITVM(4); }
            else if (w == 1) { WAITVM(2); }
            else             { WAITVM(1); }
        }
        BARRIER();   // all waves' DMA for this tile landed

        // ---- fragment reads from LDS ----
        const float* db = buf + SHD_OFF + rb_ * 96  + 6 * l;
        const float* sp = buf + SHS_OFF + rb_ * 96  + 6 * l;
        const float* rp = buf + SHR_OFF + rb_ * 288 + 18 * l;

        float2 e0 = *(const float2*)(db);
        float2 e1 = *(const float2*)(db + 2);
        float2 e2 = *(const float2*)(db + 4);
        float2 e3 = *(const float2*)(db + 6);
        float2 f0 = *(const float2*)(sp);
        float2 f1 = *(const float2*)(sp + 2);
        float2 f2v = *(const float2*)(sp + 4);
        float2 f3 = *(const float2*)(sp + 6);
        float2 c0 = *(const float2*)(rp);
        float2 c1 = *(const float2*)(rp + 2);
        float2 c2 = *(const float2*)(rp + 4);
        float2 c3 = *(const float2*)(rp + 6);
        float2 c4 = *(const float2*)(rp + 8);
        float2 c5 = *(const float2*)(rp + 10);
        float2 c6 = *(const float2*)(rp + 12);
        float2 c7 = *(const float2*)(rp + 14);
        float2 c8 = *(const float2*)(rp + 16);
        float2 c9 = *(const float2*)(rp + 18);
        float  r20 = rp[20];

        LGKM0;
        BARRIER();   // input reads done -> buf reusable for output staging

        const float D[7] = {e0.x, e0.y, e1.x, e1.y, e2.x, e2.y, e3.x};
        const float S[7] = {f0.x, f0.y, f1.x, f1.y, f2v.x, f2v.y, f3.x};
        const float R[7] = {c0.x, c1.y, c3.x, c4.y, c6.x, c7.y, c9.x};
        const float G[7] = {c0.y, c2.x, c3.y, c5.x, c6.y, c8.x, c9.y};
        const float B[7] = {c1.x, c2.y, c4.x, c5.y, c7.x, c8.y, r20};

        // ---- in-lane sequential integration over 6 (5 on lane 15) intervals ----
        float u[6];
        float Tloc = 1.0f;
        float Sw = 0.f, Sd = 0.f, Sr = 0.f, Sg = 0.f, Sbv = 0.f;

#define DO_IV(I)                                                      \
        { float delta = D[(I)+1] - D[I];                              \
          float x = 0.5f * (S[I] + S[(I)+1]) - 1.0f;                  \
          float e = one_minus_alpha(x, delta);                        \
          float uu = (1.0f - e) * Tloc;                               \
          Tloc *= e + 1e-10f;                                         \
          u[I] = uu;                                                  \
          Sw  += uu;                                                  \
          Sd  += uu * (0.5f * (D[I] + D[(I)+1]));                     \
          Sr  += uu * (0.5f * (R[I] + R[(I)+1]));                     \
          Sg  += uu * (0.5f * (G[I] + G[(I)+1]));                     \
          Sbv += uu * (0.5f * (B[I] + B[(I)+1])); }

        DO_IV(0) DO_IV(1) DO_IV(2) DO_IV(3) DO_IV(4)
        if (full) { DO_IV(5) } else { u[5] = 0.f; }
#undef DO_IV

        // ---- exclusive prefix product of segment transmittances (DPP scan) ----
        float incl = Tloc;
        incl *= DPPF(1.0f, incl, 0x111);
        incl *= DPPF(1.0f, incl, 0x112);
        incl *= DPPF(1.0f, incl, 0x114);
        incl *= DPPF(1.0f, incl, 0x118);
        float Tin = DPPF(1.0f, incl, 0x111);   // exclusive; lane0 = 1.0

        Sw *= Tin; Sd *= Tin; Sr *= Tin; Sg *= Tin; Sbv *= Tin;

#define RED(v)                         \
        v += DPPF(0.f, v, 0x111);      \
        v += DPPF(0.f, v, 0x112);      \
        v += DPPF(0.f, v, 0x114);      \
        v += DPPF(0.f, v, 0x118);
        RED(Sw) RED(Sd) RED(Sr) RED(Sg) RED(Sbv)
#undef RED

        float lo0 = 0.5f * (D[0] + D[1]);
        float lo  = DPPF(0.f, lo0, 0x11F);     // lane0 -> lane15

        // ---- stage outputs into LDS (buf[cur], input region now dead) ----
        {
            float* wst = buf + WST_OFF + rb_ * 95 + 6 * l;   // 8B-aligned
            float2* wst2 = (float2*)wst;
            wst2[0] = float2{Tin * u[0], Tin * u[1]};
            wst2[1] = float2{Tin * u[2], Tin * u[3]};
            if (full) wst2[2] = float2{Tin * u[4], Tin * u[5]};
            else      wst[4]  = Tin * u[4];
        }
        if (l == 15) {
            buf[CST_OFF + rb_ * 3 + 0] = 2.f * Sr  - 1.f;
            buf[CST_OFF + rb_ * 3 + 1] = 2.f * Sg  - 1.f;
            buf[CST_OFF + rb_ * 3 + 2] = 2.f * Sbv - 1.f;
            float dv = Sd / Sw;                    // normalize_depth
            float hi = 0.5f * (D[4] + D[5]);       // 0.5*(d[94]+d[95]) on lane 15
            dv = fmaxf(fminf(dv, hi), lo);         // NaN -> hi (ref: nan->inf->clip)
            buf[DST_OFF + rb_] = dv;
        }
        LGKM0;
        BARRIER();   // staged outputs visible to all waves

        // ---- cooperative full-line nontemporal stores (64B-aligned spans) ----
        // guaranteed per-wave NT-store counts: w0=4, w1=2, w2=1, w3=1
        {
            v4f* dst = (v4f*)(out + W_OFF + (size_t)tile * (RPB * 95));
            const v4f* src = (const v4f*)(buf + WST_OFF);
            __builtin_nontemporal_store(src[t], dst + t);                 // 4096 B
            if (t < 124) __builtin_nontemporal_store(src[256 + t], dst + 256 + t);
        }
        if (t < 12) {
            __builtin_nontemporal_store(
                ((const v4f*)(buf + CST_OFF))[t],
                (v4f*)(out + RGB_OFF + (size_t)tile * (RPB * 3)) + t);
        }
        if (t < 4) {
            __builtin_nontemporal_store(
                ((const v4f*)(buf + DST_OFF))[t],
                (v4f*)(out + DEPTH_OFF + (size_t)tile * RPB) + t);
        }
        LGKM0;
        BARRIER();   // store-side LDS reads retired -> buf free for tile i+2
    }
}

extern "C" void kernel_launch(void* const* d_in, const int* in_sizes, int n_in,
                              void* d_out, int out_size, void* d_ws, size_t ws_size,
                              hipStream_t stream) {
    const float* rgbs   = (const float*)d_in[0];
    const float* sigmas = (const float*)d_in[1];
    const float* depths = (const float*)d_in[2];
    float* out = (float*)d_out;

    // 512 persistent blocks (2/CU at 61.6 KB LDS), 8 tiles of 16 rays each
    integrate_kernel<<<NBLOCKS, 256, 0, stream>>>(rgbs, sigmas, depths, out);
}

// Round 3
// 148.880 us; speedup vs baseline: 1.0332x; 1.0332x over previous
//
#include <hip/hip_runtime.h>
#include <math.h>

// N=4, R=16384, K=96. Output: rgb [65536*3] | depth [65536] | weights [65536*95]
#define NRAYS     65536
#define RGB_OFF   0
#define DEPTH_OFF (NRAYS * 3)
#define W_OFF     (NRAYS * 4)

#define RPB 16               // rays per block (256 threads, 4 waves, 4 rays/wave)
// input staging layout (floats); pads absorb lane-15 overreads
#define SHD_OFF 0            // 16*96 = 1536 used, pad to 1540
#define SHS_OFF 1540
#define SHR_OFF 3080         // 16*288 = 4608 used, pad to 4616
#define SH_TOTAL 7696        // 30784 B -> 5 blocks/CU (20 waves)

typedef float v4f __attribute__((ext_vector_type(4)));

#define DPPF(oldv, x, ctrl)                                                    \
    __int_as_float(__builtin_amdgcn_update_dpp(                                \
        __float_as_int(oldv), __float_as_int(x), (ctrl), 0xF, 0xF, false))

#define WAITVM(N) asm volatile("s_waitcnt vmcnt(" #N ")" ::: "memory")
#define LGKM0     asm volatile("s_waitcnt lgkmcnt(0)" ::: "memory")
// compiler-level fence: pins intrinsic memory-op order at IR (asm memory
// clobber) AND MachineScheduler (sched_barrier(0)) level. No runtime cost.
#define SCHED_PIN()                                                            \
    do { asm volatile("" ::: "memory");                                        \
         __builtin_amdgcn_sched_barrier(0); } while (0)

// 1-alpha = exp(-delta*softplus(x)) via HW transcendentals. absmax 7.8e-3 ok.
__device__ __forceinline__ float one_minus_alpha(float x, float delta) {
    const float L2E = 1.44269504088896340736f;
    float xl = x * L2E;
    float l2 = (x > 20.0f) ? xl
                           : __builtin_amdgcn_logf(1.0f + __builtin_amdgcn_exp2f(xl));
    return __builtin_amdgcn_exp2f(-delta * l2);
}

// async global->LDS DMA, aux=2 -> NT (streaming): inputs are read once.
// Full-wave only (exec-masked global_load_lds is NOT verified on gfx950 —
// R10's masked half-chunks corrupted LDS).
__device__ __forceinline__ void gload_lds16(const float* g, float* l) {
    __builtin_amdgcn_global_load_lds(
        (const __attribute__((address_space(1))) void*)g,
        (__attribute__((address_space(3))) void*)l, 16, 0, 2);
}
__device__ __forceinline__ void gload_lds4(const float* g, float* l) {
    __builtin_amdgcn_global_load_lds(
        (const __attribute__((address_space(1))) void*)g,
        (__attribute__((address_space(3))) void*)l, 4, 0, 2);
}

// ---------------------------------------------------------------------------
// R11 = R10 intent (wave-decoupled, zero barriers) with the two unverified
// mechanisms removed:
//  - ALL DMA chunks are full-wave: 384-float slices = 1x16B/lane + 2x4B/lane;
//    rgb 1152-float slice = 4x16B/lane + 2x4B/lane. No exec-masked DMA.
//  - issue order d,s | rgb is PINNED with asm-memory-clobber +
//    sched_barrier(0) so the split wait vmcnt(6) provably means d+s landed.
//  - split wait: pass 1 (transcendentals, Tin scan, Sw/Sd) runs while the 6
//    rgb chunks are still in flight; vmcnt(0) before the color pass.
//  - outputs staged into the wave's OWN dead input slices; per-wave NT
//    stores (95+3+1 dwordx4). No __syncthreads anywhere.
// ---------------------------------------------------------------------------
__global__ __launch_bounds__(256) void integrate_kernel(
    const float* __restrict__ rgbs,     // [NRAYS, 96, 3]
    const float* __restrict__ sigmas,   // [NRAYS, 96]
    const float* __restrict__ depths,   // [NRAYS, 96]
    float* __restrict__ out)
{
    __shared__ float sh[SH_TOTAL];

    const int t   = threadIdx.x;
    const int w   = t >> 6;
    const int l64 = t & 63;
    // XCD-contiguous swizzle: 4096 blocks = 8 XCDs x 512 contiguous
    const int blk = ((blockIdx.x & 7) << 9) | (blockIdx.x >> 3);

    // ---- per-wave async NT staging of its own 4 rays (7680 B) ----
    {
        const float* gd = depths + (size_t)blk * (RPB * 96)  + w * 384;
        const float* gs = sigmas + (size_t)blk * (RPB * 96)  + w * 384;
        const float* gr = rgbs   + (size_t)blk * (RPB * 288) + w * 1152;
        float* dd  = sh + SHD_OFF + w * 384;
        float* dsg = sh + SHS_OFF + w * 384;
        float* dr  = sh + SHR_OFF + w * 1152;

        // group 1: d then s (6 full-wave issues)
        gload_lds16(gd + l64 * 4, dd + l64 * 4);              // d[0,256)
        gload_lds4 (gd + 256 + l64, dd + 256 + l64);          // d[256,320)
        gload_lds4 (gd + 320 + l64, dd + 320 + l64);          // d[320,384)
        gload_lds16(gs + l64 * 4, dsg + l64 * 4);             // s[0,256)
        gload_lds4 (gs + 256 + l64, dsg + 256 + l64);
        gload_lds4 (gs + 320 + l64, dsg + 320 + l64);

        SCHED_PIN();   // group 1 strictly older than group 2 in vmcnt order

        // group 2: rgb (6 full-wave issues)
#pragma unroll
        for (int c = 0; c < 4; ++c)
            gload_lds16(gr + c * 256 + l64 * 4, dr + c * 256 + l64 * 4);
        gload_lds4(gr + 1024 + l64, dr + 1024 + l64);
        gload_lds4(gr + 1088 + l64, dr + 1088 + l64);

        SCHED_PIN();   // nothing from either group sinks below the waits
    }

    const int rb_  = t >> 4;            // ray within block
    const int rloc = rb_ & 3;           // ray within wave
    const int l    = t & 15;            // segment within ray
    const bool full = (l < 15);

    // ---- wait for group 1 only (rgb's 6 issues still in flight) ----
    WAITVM(6);

    const float* db = sh + SHD_OFF + rb_ * 96 + 6 * l;
    const float* sp = sh + SHS_OFF + rb_ * 96 + 6 * l;

    float2 e0 = *(const float2*)(db);
    float2 e1 = *(const float2*)(db + 2);
    float2 e2 = *(const float2*)(db + 4);
    float2 e3 = *(const float2*)(db + 6);
    float2 f0 = *(const float2*)(sp);
    float2 f1 = *(const float2*)(sp + 2);
    float2 f2v = *(const float2*)(sp + 4);
    float2 f3 = *(const float2*)(sp + 6);
    LGKM0;

    const float D[7] = {e0.x, e0.y, e1.x, e1.y, e2.x, e2.y, e3.x};
    const float S[7] = {f0.x, f0.y, f1.x, f1.y, f2v.x, f2v.y, f3.x};

    // ---- pass 1: alpha/transmittance (transcendental-heavy) + Sw, Sd ----
    float u[6];
    float Tloc = 1.0f;
    float Sw = 0.f, Sd = 0.f;

#define DO_A(I)                                                       \
    { float delta = D[(I)+1] - D[I];                                  \
      float x = 0.5f * (S[I] + S[(I)+1]) - 1.0f;                      \
      float e = one_minus_alpha(x, delta);                            \
      float uu = (1.0f - e) * Tloc;                                   \
      Tloc *= e + 1e-10f;                                             \
      u[I] = uu;                                                      \
      Sw  += uu;                                                      \
      Sd  += uu * (0.5f * (D[I] + D[(I)+1])); }

    DO_A(0) DO_A(1) DO_A(2) DO_A(3) DO_A(4)
    if (full) { DO_A(5) } else { u[5] = 0.f; }
#undef DO_A

    // ---- exclusive prefix product of segment transmittances (DPP row scan)
    float incl = Tloc;
    incl *= DPPF(1.0f, incl, 0x111);
    incl *= DPPF(1.0f, incl, 0x112);
    incl *= DPPF(1.0f, incl, 0x114);
    incl *= DPPF(1.0f, incl, 0x118);
    float Tin = DPPF(1.0f, incl, 0x111);   // exclusive; lane0 = 1.0

    Sw *= Tin; Sd *= Tin;

#define RED(v)                         \
    v += DPPF(0.f, v, 0x111);          \
    v += DPPF(0.f, v, 0x112);          \
    v += DPPF(0.f, v, 0x114);          \
    v += DPPF(0.f, v, 0x118);
    RED(Sw) RED(Sd)

    float lo0 = 0.5f * (D[0] + D[1]);
    float lo  = DPPF(0.f, lo0, 0x11F);     // lane0 -> lane15

    // ---- rgb has had pass-1 latency to land; finish the color pass ----
    WAITVM(0);
    const float* rp = sh + SHR_OFF + rb_ * 288 + 18 * l;
    float2 c0 = *(const float2*)(rp);
    float2 c1 = *(const float2*)(rp + 2);
    float2 c2 = *(const float2*)(rp + 4);
    float2 c3 = *(const float2*)(rp + 6);
    float2 c4 = *(const float2*)(rp + 8);
    float2 c5 = *(const float2*)(rp + 10);
    float2 c6 = *(const float2*)(rp + 12);
    float2 c7 = *(const float2*)(rp + 14);
    float2 c8 = *(const float2*)(rp + 16);
    float2 c9 = *(const float2*)(rp + 18);
    float  r20 = rp[20];
    LGKM0;

    const float R[7] = {c0.x, c1.y, c3.x, c4.y, c6.x, c7.y, c9.x};
    const float G[7] = {c0.y, c2.x, c3.y, c5.x, c6.y, c8.x, c9.y};
    const float B[7] = {c1.x, c2.y, c4.x, c5.y, c7.x, c8.y, r20};

    float Sr = 0.f, Sg = 0.f, Sbv = 0.f;
#define DO_B(I)                                                       \
    { Sr  += u[I] * (0.5f * (R[I] + R[(I)+1]));                       \
      Sg  += u[I] * (0.5f * (G[I] + G[(I)+1]));                       \
      Sbv += u[I] * (0.5f * (B[I] + B[(I)+1])); }
    DO_B(0) DO_B(1) DO_B(2) DO_B(3) DO_B(4)
    if (full) { DO_B(5) }   // guard: R[6]/G[6]/B[6] are garbage on lane 15
#undef DO_B

    Sr *= Tin; Sg *= Tin; Sbv *= Tin;
    RED(Sr) RED(Sg) RED(Sbv)
#undef RED

    // ---- stage outputs into this wave's OWN dead input slices ----
    // weights (380 floats) -> its D slice (384 floats)
    {
        float* wst = sh + SHD_OFF + w * 384 + rloc * 95 + 6 * l;
        float2* wst2 = (float2*)wst;
        wst2[0] = float2{Tin * u[0], Tin * u[1]};
        wst2[1] = float2{Tin * u[2], Tin * u[3]};
        if (full) wst2[2] = float2{Tin * u[4], Tin * u[5]};
        else      wst[4]  = Tin * u[4];
    }
    // rgb (12 floats) + depth (4 floats) -> its S slice
    if (l == 15) {
        float* cst = sh + SHS_OFF + w * 384;
        cst[rloc * 3 + 0] = 2.f * Sr  - 1.f;
        cst[rloc * 3 + 1] = 2.f * Sg  - 1.f;
        cst[rloc * 3 + 2] = 2.f * Sbv - 1.f;
        float dv = Sd / Sw;                    // normalize_depth
        float hi = 0.5f * (D[4] + D[5]);       // 0.5*(d[94]+d[95]) on lane 15
        dv = fmaxf(fminf(dv, hi), lo);         // NaN -> hi (ref: nan->inf->clip)
        cst[12 + rloc] = dv;
    }
    LGKM0;   // wave-local ds_writes visible to wave-local readback

    // ---- per-wave cooperative NT stores (all spans 16B-aligned) ----
    {
        // weights: 380 floats = 95 dwordx4 per wave
        const v4f* src = (const v4f*)(sh + SHD_OFF + w * 384);
        v4f* dst = (v4f*)(out + W_OFF + ((size_t)blk * RPB + 4 * w) * 95);
        __builtin_nontemporal_store(src[l64], dst + l64);
        if (l64 < 31) __builtin_nontemporal_store(src[64 + l64], dst + 64 + l64);
    }
    if (l64 < 3) {   // rgb: 12 floats = 3 dwordx4
        __builtin_nontemporal_store(
            ((const v4f*)(sh + SHS_OFF + w * 384))[l64],
            (v4f*)(out + RGB_OFF + ((size_t)blk * RPB + 4 * w) * 3) + l64);
    }
    if (l64 == 3) {  // depth: 4 floats = 1 dwordx4
        __builtin_nontemporal_store(
            ((const v4f*)(sh + SHS_OFF + w * 384 + 12))[0],
            (v4f*)(out + DEPTH_OFF + (size_t)blk * RPB + 4 * w));
    }
}

extern "C" void kernel_launch(void* const* d_in, const int* in_sizes, int n_in,
                              void* d_out, int out_size, void* d_ws, size_t ws_size,
                              hipStream_t stream) {
    const float* rgbs   = (const float*)d_in[0];
    const float* sigmas = (const float*)d_in[1];
    const float* depths = (const float*)d_in[2];
    float* out = (float*)d_out;

    // 16 rays per 256-thread block -> 4096 blocks, 5 blocks/CU resident
    integrate_kernel<<<NRAYS / RPB, 256, 0, stream>>>(rgbs, sigmas, depths, out);
}